// Round 1
// baseline (241.194 us; speedup 1.0000x reference)
//
#include <hip/hip_runtime.h>
#include <hip/hip_bf16.h>
#include <stdint.h>

typedef __attribute__((ext_vector_type(8))) short bf16x8;
typedef __attribute__((ext_vector_type(4))) float f32x4;

#define DEV static __device__ __forceinline__

constexpr int DM = 1024;   // d_model
constexpr int LQ = 2048;   // seq len
constexpr int NB = 2;      // batch
constexpr int NHD = 16;    // heads
constexpr int DH = 64;     // head dim
constexpr int MT = NB * LQ; // 4096 total rows

DEV unsigned short f2bf(float f) {
  union { float f; unsigned u; } x; x.f = f;
  unsigned r = x.u + 0x7fffu + ((x.u >> 16) & 1u);
  return (unsigned short)(r >> 16);
}

DEV f32x4 MFMA(bf16x8 a, bf16x8 b, f32x4 c) {
  return __builtin_amdgcn_mfma_f32_16x16x32_bf16(a, b, c, 0, 0, 0);
}

// ---------------- f32 -> bf16 conversion (8 elems/thread) ----------------
__global__ void cvt_f32_bf16(const float* __restrict__ in,
                             unsigned short* __restrict__ out) {
  long i = ((long)blockIdx.x * blockDim.x + threadIdx.x) * 8;
  f32x4 a = *(const f32x4*)(in + i);
  f32x4 b = *(const f32x4*)(in + i + 4);
  bf16x8 r;
#pragma unroll
  for (int e = 0; e < 4; ++e) {
    r[e]     = (short)f2bf(a[e]);
    r[e + 4] = (short)f2bf(b[e]);
  }
  *(bf16x8*)(out + i) = r;
}

// ---------------- NT GEMM: C[M][N] = A[M][K] * W[N][K]^T + bias ----------
// MODE 0: store bf16 row-major [M][DM]
// MODE 1: store bf16 transposed per head: out[b][h][d][L]  (V projection)
// MODE 2: store f32 row-major [M][DM]  (final output)
template<int MODE>
__global__ __launch_bounds__(256)
void gemm_nt(const unsigned short* __restrict__ A,
             const unsigned short* __restrict__ W,
             const float* __restrict__ bias,
             void* __restrict__ outp) {
  constexpr int K = DM, N = DM;
  __shared__ short As[128][72];   // +8 pad: stride 144B kills 16-way conflicts
  __shared__ short Bs[128][72];
  const int tid = threadIdx.x;
  const int lane = tid & 63, wave = tid >> 6;
  const int wr = wave >> 1, wc = wave & 1;
  const int g = lane >> 4, c = lane & 15;
  const long m0 = (long)blockIdx.y * 128, n0 = (long)blockIdx.x * 128;
  const int srow = tid >> 2;        // 0..63
  const int scol = (tid & 3) * 8;   // 0,8,16,24

  const unsigned short* Ap = A + (m0 + srow) * K + scol;
  const unsigned short* Wp = W + (n0 + srow) * K + scol;

  f32x4 acc[4][4] = {};
  bf16x8 pa0, pa1, pb0, pb1;
  pa0 = *(const bf16x8*)(Ap);
  pa1 = *(const bf16x8*)(Ap + 64 * K);
  pb0 = *(const bf16x8*)(Wp);
  pb1 = *(const bf16x8*)(Wp + 64 * K);

  for (int ks = 0; ks < K / 32; ++ks) {
    __syncthreads();
    *(bf16x8*)&As[srow][scol]      = pa0;
    *(bf16x8*)&As[srow + 64][scol] = pa1;
    *(bf16x8*)&Bs[srow][scol]      = pb0;
    *(bf16x8*)&Bs[srow + 64][scol] = pb1;
    __syncthreads();
    if (ks + 1 < K / 32) {
      const unsigned short* a2 = Ap + (ks + 1) * 32;
      const unsigned short* w2 = Wp + (ks + 1) * 32;
      pa0 = *(const bf16x8*)(a2);
      pa1 = *(const bf16x8*)(a2 + 64 * K);
      pb0 = *(const bf16x8*)(w2);
      pb1 = *(const bf16x8*)(w2 + 64 * K);
    }
    bf16x8 af[4], bfr[4];
#pragma unroll
    for (int i = 0; i < 4; ++i)
      af[i] = *(const bf16x8*)&As[wr * 64 + i * 16 + c][g * 8];
#pragma unroll
    for (int j = 0; j < 4; ++j)
      bfr[j] = *(const bf16x8*)&Bs[wc * 64 + j * 16 + c][g * 8];
#pragma unroll
    for (int i = 0; i < 4; ++i)
#pragma unroll
      for (int j = 0; j < 4; ++j)
        acc[i][j] = MFMA(af[i], bfr[j], acc[i][j]);
  }

#pragma unroll
  for (int i = 0; i < 4; ++i) {
#pragma unroll
    for (int j = 0; j < 4; ++j) {
      const int n = (int)n0 + wc * 64 + j * 16 + c;
      const float bv = bias[n];
#pragma unroll
      for (int r = 0; r < 4; ++r) {
        const int m = (int)m0 + wr * 64 + i * 16 + g * 4 + r;
        const float val = acc[i][j][r] + bv;
        if (MODE == 0) {
          ((unsigned short*)outp)[(long)m * N + n] = f2bf(val);
        } else if (MODE == 1) {
          const int b = m >> 11, l = m & 2047;
          const int h = n >> 6,  d = n & 63;
          ((unsigned short*)outp)[(((long)(b * NHD + h)) * DH + d) * LQ + l] = f2bf(val);
        } else {
          ((float*)outp)[(long)m * N + n] = val;
        }
      }
    }
  }
}

// ---------------- causal flash attention ---------------------------------
// block: 256 threads (4 waves). Each block: one (b,h), 64 q rows.
// wave w owns q rows [16w, 16w+16). Online softmax per row in registers.
__global__ __launch_bounds__(256)
void attn_kernel(const unsigned short* __restrict__ Qp,
                 const unsigned short* __restrict__ Kp,
                 const unsigned short* __restrict__ Vt,
                 unsigned short* __restrict__ Ob) {
  __shared__ short Qs[64][72], Ks[64][72], Vs[64][72], Ps[64][72];
  const int tid = threadIdx.x;
  const int lane = tid & 63, wave = tid >> 6;
  const int g = lane >> 4, c = lane & 15;
  const int qb = blockIdx.x;      // 0..31
  const int bh = blockIdx.y;      // 0..31
  const int b = bh >> 4, h = bh & 15;
  const int q0 = qb * 64;

  const int lrow = tid >> 3;        // 0..31
  const int lcol = (tid & 7) * 8;   // 0..56

  // stage Q (once)
  {
    const unsigned short* src =
        Qp + ((long)(b * LQ + q0 + lrow)) * DM + h * DH + lcol;
    *(bf16x8*)&Qs[lrow][lcol]      = *(const bf16x8*)src;
    *(bf16x8*)&Qs[lrow + 32][lcol] = *(const bf16x8*)(src + 32 * DM);
  }
  __syncthreads();
  bf16x8 qf0 = *(const bf16x8*)&Qs[16 * wave + c][g * 8];
  bf16x8 qf1 = *(const bf16x8*)&Qs[16 * wave + c][32 + g * 8];

  float mrow[4], lsum[4];
#pragma unroll
  for (int r = 0; r < 4; ++r) { mrow[r] = -1e30f; lsum[r] = 0.f; }
  f32x4 oacc[4] = {};

  const unsigned short* Kbase = Kp + ((long)(b * LQ)) * DM + h * DH;
  const unsigned short* Vbase = Vt + (long)bh * DH * LQ;

  for (int j = 0; j <= qb; ++j) {
    const int kv0 = j * 64;
    // stage K tile [64 kv][64 k] and V^T tile [64 d][64 kv]
    {
      const unsigned short* ksrc = Kbase + (long)(kv0 + lrow) * DM + lcol;
      *(bf16x8*)&Ks[lrow][lcol]      = *(const bf16x8*)ksrc;
      *(bf16x8*)&Ks[lrow + 32][lcol] = *(const bf16x8*)(ksrc + 32 * DM);
      const unsigned short* vsrc = Vbase + (long)lrow * LQ + kv0 + lcol;
      *(bf16x8*)&Vs[lrow][lcol]      = *(const bf16x8*)vsrc;
      *(bf16x8*)&Vs[lrow + 32][lcol] = *(const bf16x8*)(vsrc + 32 * LQ);
    }
    __syncthreads();

    // S = Q K^T : wave computes 16 q rows x 64 kv
    f32x4 sacc[4] = {};
#pragma unroll
    for (int jt = 0; jt < 4; ++jt) {
      bf16x8 kf0 = *(const bf16x8*)&Ks[jt * 16 + c][g * 8];
      bf16x8 kf1 = *(const bf16x8*)&Ks[jt * 16 + c][32 + g * 8];
      sacc[jt] = MFMA(qf0, kf0, sacc[jt]);
      sacc[jt] = MFMA(qf1, kf1, sacc[jt]);
    }

    // scale + causal mask + row max
    float rmax[4];
#pragma unroll
    for (int r = 0; r < 4; ++r) rmax[r] = -1e30f;
#pragma unroll
    for (int jt = 0; jt < 4; ++jt) {
#pragma unroll
      for (int r = 0; r < 4; ++r) {
        float s = sacc[jt][r] * 0.125f;
        const int kvi = kv0 + jt * 16 + c;
        const int qi  = q0 + 16 * wave + g * 4 + r;
        s = (kvi <= qi) ? s : -1e30f;
        sacc[jt][r] = s;
        rmax[r] = fmaxf(rmax[r], s);
      }
    }
#pragma unroll
    for (int mk = 1; mk <= 8; mk <<= 1)
#pragma unroll
      for (int r = 0; r < 4; ++r)
        rmax[r] = fmaxf(rmax[r], __shfl_xor(rmax[r], mk, 64));

    float scl[4];
#pragma unroll
    for (int r = 0; r < 4; ++r) {
      const float mn = fmaxf(mrow[r], rmax[r]);
      scl[r] = __expf(mrow[r] - mn);
      mrow[r] = mn;
    }
    float rsum[4] = {0.f, 0.f, 0.f, 0.f};
#pragma unroll
    for (int jt = 0; jt < 4; ++jt) {
#pragma unroll
      for (int r = 0; r < 4; ++r) {
        const float p = __expf(sacc[jt][r] - mrow[r]);
        sacc[jt][r] = p;
        rsum[r] += p;
      }
    }
#pragma unroll
    for (int mk = 1; mk <= 8; mk <<= 1)
#pragma unroll
      for (int r = 0; r < 4; ++r)
        rsum[r] += __shfl_xor(rsum[r], mk, 64);
#pragma unroll
    for (int r = 0; r < 4; ++r) lsum[r] = lsum[r] * scl[r] + rsum[r];

    // write P (bf16) — each wave writes only its own 16 rows
#pragma unroll
    for (int jt = 0; jt < 4; ++jt)
#pragma unroll
      for (int r = 0; r < 4; ++r)
        Ps[16 * wave + g * 4 + r][jt * 16 + c] = (short)f2bf(sacc[jt][r]);

    // rescale O
#pragma unroll
    for (int dj = 0; dj < 4; ++dj)
#pragma unroll
      for (int r = 0; r < 4; ++r) oacc[dj][r] *= scl[r];

    // O += P * V   (P rows are wave-private; within-wave LDS dep)
    bf16x8 pf0 = *(const bf16x8*)&Ps[16 * wave + c][g * 8];
    bf16x8 pf1 = *(const bf16x8*)&Ps[16 * wave + c][32 + g * 8];
#pragma unroll
    for (int dj = 0; dj < 4; ++dj) {
      bf16x8 vf0 = *(const bf16x8*)&Vs[dj * 16 + c][g * 8];
      bf16x8 vf1 = *(const bf16x8*)&Vs[dj * 16 + c][32 + g * 8];
      oacc[dj] = MFMA(pf0, vf0, oacc[dj]);
      oacc[dj] = MFMA(pf1, vf1, oacc[dj]);
    }
    __syncthreads();   // protect Ks/Vs before next stage
  }

  // epilogue: O /= lsum, store bf16 [b][l][DM]
#pragma unroll
  for (int dj = 0; dj < 4; ++dj) {
#pragma unroll
    for (int r = 0; r < 4; ++r) {
      const float o = oacc[dj][r] / lsum[r];
      const int l = q0 + 16 * wave + g * 4 + r;
      const int n = h * DH + dj * 16 + c;
      Ob[((long)(b * LQ + l)) * DM + n] = f2bf(o);
    }
  }
}

// ---------------- launch --------------------------------------------------
extern "C" void kernel_launch(void* const* d_in, const int* in_sizes, int n_in,
                              void* d_out, int out_size, void* d_ws, size_t ws_size,
                              hipStream_t stream) {
  const float* q  = (const float*)d_in[0];
  const float* k  = (const float*)d_in[1];
  const float* v  = (const float*)d_in[2];
  const float* Wq = (const float*)d_in[3];
  const float* bq = (const float*)d_in[4];
  const float* Wk = (const float*)d_in[5];
  const float* bk = (const float*)d_in[6];
  const float* Wv = (const float*)d_in[7];
  const float* bv = (const float*)d_in[8];
  const float* Wo = (const float*)d_in[9];
  const float* bo = (const float*)d_in[10];

  unsigned short* ws = (unsigned short*)d_ws;
  const long NQKV = (long)MT * DM;   // 4,194,304 elems
  const long NW   = (long)DM * DM;   // 1,048,576 elems
  unsigned short* QB  = ws;          // q bf16 (reused as attn-out later)
  unsigned short* KB  = QB + NQKV;
  unsigned short* VB  = KB + NQKV;
  unsigned short* WQb = VB + NQKV;
  unsigned short* WKb = WQb + NW;
  unsigned short* WVb = WKb + NW;
  unsigned short* WOb = WVb + NW;
  unsigned short* QP  = WOb + NW;
  unsigned short* KP  = QP + NQKV;
  unsigned short* VT  = KP + NQKV;
  unsigned short* OB  = QB;          // alias: q bf16 dead after Q projection

  cvt_f32_bf16<<<(int)(NQKV / 2048), 256, 0, stream>>>(q, QB);
  cvt_f32_bf16<<<(int)(NQKV / 2048), 256, 0, stream>>>(k, KB);
  cvt_f32_bf16<<<(int)(NQKV / 2048), 256, 0, stream>>>(v, VB);
  cvt_f32_bf16<<<(int)(NW / 2048),   256, 0, stream>>>(Wq, WQb);
  cvt_f32_bf16<<<(int)(NW / 2048),   256, 0, stream>>>(Wk, WKb);
  cvt_f32_bf16<<<(int)(NW / 2048),   256, 0, stream>>>(Wv, WVb);
  cvt_f32_bf16<<<(int)(NW / 2048),   256, 0, stream>>>(Wo, WOb);

  dim3 ggrid(8, 32);
  gemm_nt<0><<<ggrid, 256, 0, stream>>>(QB, WQb, bq, QP);
  gemm_nt<0><<<ggrid, 256, 0, stream>>>(KB, WKb, bk, KP);
  gemm_nt<1><<<ggrid, 256, 0, stream>>>(VB, WVb, bv, VT);

  attn_kernel<<<dim3(32, 32), 256, 0, stream>>>(QP, KP, VT, OB);

  gemm_nt<2><<<ggrid, 256, 0, stream>>>(OB, WOb, bo, d_out);
}

// Round 2
// 147.264 us; speedup vs baseline: 1.6378x; 1.6378x over previous
//
#include <hip/hip_runtime.h>
#include <hip/hip_bf16.h>
#include <stdint.h>

typedef __attribute__((ext_vector_type(8))) short bf16x8;
typedef __attribute__((ext_vector_type(4))) float f32x4;

#define DEV static __device__ __forceinline__

constexpr int DM = 1024;   // d_model
constexpr int LQ = 2048;   // seq len
constexpr int NB = 2;      // batch
constexpr int NHD = 16;    // heads
constexpr int DH = 64;     // head dim
constexpr int MT = NB * LQ; // 4096 total rows

constexpr float SCL2 = 0.125f * 1.4426950408889634f; // (1/sqrt(Dh)) * log2(e)

DEV unsigned short f2bf(float f) {
  union { float f; unsigned u; } x; x.f = f;
  unsigned r = x.u + 0x7fffu + ((x.u >> 16) & 1u);
  return (unsigned short)(r >> 16);
}

DEV f32x4 MFMA(bf16x8 a, bf16x8 b, f32x4 c) {
  return __builtin_amdgcn_mfma_f32_16x16x32_bf16(a, b, c, 0, 0, 0);
}

// ---------------- f32 -> bf16 conversion ---------------------------------
DEV void cvt_body(const float* __restrict__ in, unsigned short* __restrict__ out) {
  long i = ((long)blockIdx.x * blockDim.x + threadIdx.x) * 8;
  f32x4 a = *(const f32x4*)(in + i);
  f32x4 b = *(const f32x4*)(in + i + 4);
  bf16x8 r;
#pragma unroll
  for (int e = 0; e < 4; ++e) {
    r[e]     = (short)f2bf(a[e]);
    r[e + 4] = (short)f2bf(b[e]);
  }
  *(bf16x8*)(out + i) = r;
}

__global__ void cvt3(const float* __restrict__ a, const float* __restrict__ b,
                     const float* __restrict__ c,
                     unsigned short* oa, unsigned short* ob, unsigned short* oc) {
  const float* src = blockIdx.y == 0 ? a : blockIdx.y == 1 ? b : c;
  unsigned short* dst = blockIdx.y == 0 ? oa : blockIdx.y == 1 ? ob : oc;
  cvt_body(src, dst);
}

__global__ void cvt4(const float* __restrict__ a, const float* __restrict__ b,
                     const float* __restrict__ c, const float* __restrict__ d,
                     unsigned short* oa, unsigned short* ob,
                     unsigned short* oc, unsigned short* od) {
  const float* src = blockIdx.y == 0 ? a : blockIdx.y == 1 ? b
                   : blockIdx.y == 2 ? c : d;
  unsigned short* dst = blockIdx.y == 0 ? oa : blockIdx.y == 1 ? ob
                      : blockIdx.y == 2 ? oc : od;
  cvt_body(src, dst);
}

// ---------------- NT GEMM core: C[M][N] = A[M][K] * W[N][K]^T + bias -----
// mode 0: bf16 row-major [M][DM]; mode 1: bf16 V^T per head [b][h][d][L];
// mode 2: f32 row-major.
DEV void gemm_core(short (*As)[72], short (*Bs)[72],
                   const unsigned short* __restrict__ A,
                   const unsigned short* __restrict__ W,
                   const float* __restrict__ bias,
                   void* __restrict__ outp, int mode) {
  constexpr int K = DM, N = DM;
  const int tid = threadIdx.x;
  const int lane = tid & 63, wave = tid >> 6;
  const int wr = wave >> 1, wc = wave & 1;
  const int g = lane >> 4, c = lane & 15;
  const long m0 = (long)blockIdx.y * 128, n0 = (long)blockIdx.x * 128;
  const int srow = tid >> 2;        // 0..63
  const int scol = (tid & 3) * 8;   // 0,8,16,24

  const unsigned short* Ap = A + (m0 + srow) * K + scol;
  const unsigned short* Wp = W + (n0 + srow) * K + scol;

  f32x4 acc[4][4] = {};
  bf16x8 pa0, pa1, pb0, pb1;
  pa0 = *(const bf16x8*)(Ap);
  pa1 = *(const bf16x8*)(Ap + 64 * K);
  pb0 = *(const bf16x8*)(Wp);
  pb1 = *(const bf16x8*)(Wp + 64 * K);

  for (int ks = 0; ks < K / 32; ++ks) {
    __syncthreads();
    *(bf16x8*)&As[srow][scol]      = pa0;
    *(bf16x8*)&As[srow + 64][scol] = pa1;
    *(bf16x8*)&Bs[srow][scol]      = pb0;
    *(bf16x8*)&Bs[srow + 64][scol] = pb1;
    __syncthreads();
    if (ks + 1 < K / 32) {
      const unsigned short* a2 = Ap + (ks + 1) * 32;
      const unsigned short* w2 = Wp + (ks + 1) * 32;
      pa0 = *(const bf16x8*)(a2);
      pa1 = *(const bf16x8*)(a2 + 64 * K);
      pb0 = *(const bf16x8*)(w2);
      pb1 = *(const bf16x8*)(w2 + 64 * K);
    }
    bf16x8 af[4], bfr[4];
#pragma unroll
    for (int i = 0; i < 4; ++i)
      af[i] = *(const bf16x8*)&As[wr * 64 + i * 16 + c][g * 8];
#pragma unroll
    for (int j = 0; j < 4; ++j)
      bfr[j] = *(const bf16x8*)&Bs[wc * 64 + j * 16 + c][g * 8];
#pragma unroll
    for (int i = 0; i < 4; ++i)
#pragma unroll
      for (int j = 0; j < 4; ++j)
        acc[i][j] = MFMA(af[i], bfr[j], acc[i][j]);
  }

  if (mode == 0) {
#pragma unroll
    for (int i = 0; i < 4; ++i)
#pragma unroll
      for (int j = 0; j < 4; ++j) {
        const int n = (int)n0 + wc * 64 + j * 16 + c;
        const float bv = bias[n];
#pragma unroll
        for (int r = 0; r < 4; ++r) {
          const int m = (int)m0 + wr * 64 + i * 16 + g * 4 + r;
          ((unsigned short*)outp)[(long)m * N + n] = f2bf(acc[i][j][r] + bv);
        }
      }
  } else if (mode == 1) {
#pragma unroll
    for (int i = 0; i < 4; ++i)
#pragma unroll
      for (int j = 0; j < 4; ++j) {
        const int n = (int)n0 + wc * 64 + j * 16 + c;
        const float bv = bias[n];
        const int h = n >> 6, d = n & 63;
#pragma unroll
        for (int r = 0; r < 4; ++r) {
          const int m = (int)m0 + wr * 64 + i * 16 + g * 4 + r;
          const int b = m >> 11, l = m & 2047;
          ((unsigned short*)outp)[(((long)(b * NHD + h)) * DH + d) * LQ + l] =
              f2bf(acc[i][j][r] + bv);
        }
      }
  } else {
#pragma unroll
    for (int i = 0; i < 4; ++i)
#pragma unroll
      for (int j = 0; j < 4; ++j) {
        const int n = (int)n0 + wc * 64 + j * 16 + c;
        const float bv = bias[n];
#pragma unroll
        for (int r = 0; r < 4; ++r) {
          const int m = (int)m0 + wr * 64 + i * 16 + g * 4 + r;
          ((float*)outp)[(long)m * N + n] = acc[i][j][r] + bv;
        }
      }
  }
}

__global__ __launch_bounds__(256)
void qkv_proj(const unsigned short* __restrict__ QB,
              const unsigned short* __restrict__ KB,
              const unsigned short* __restrict__ VB,
              const unsigned short* __restrict__ WQb,
              const unsigned short* __restrict__ WKb,
              const unsigned short* __restrict__ WVb,
              const float* __restrict__ bq, const float* __restrict__ bk,
              const float* __restrict__ bv,
              unsigned short* QP, unsigned short* KP, unsigned short* VT) {
  __shared__ short As[128][72];
  __shared__ short Bs[128][72];
  const int z = blockIdx.z;
  const unsigned short* A = z == 0 ? QB : z == 1 ? KB : VB;
  const unsigned short* W = z == 0 ? WQb : z == 1 ? WKb : WVb;
  const float* bias = z == 0 ? bq : z == 1 ? bk : bv;
  void* out = z == 0 ? (void*)QP : z == 1 ? (void*)KP : (void*)VT;
  gemm_core(As, Bs, A, W, bias, out, z == 2 ? 1 : 0);
}

__global__ __launch_bounds__(256)
void oproj(const unsigned short* __restrict__ A,
           const unsigned short* __restrict__ W,
           const float* __restrict__ bias, float* out) {
  __shared__ short As[128][72];
  __shared__ short Bs[128][72];
  gemm_core(As, Bs, A, W, bias, out, 2);
}

// ---------------- causal flash attention v2 ------------------------------
// Swapped QK^T: sacc = mfma(K_frag, Q_frag) => lane (g,c) holds
// S[q = qtile+c][kv = 16*jt + 4*g + r]. Softmax per lane-row, reduce over
// the 4 g-lanes (shfl_xor 16,32). P packed to LDS (b64), PV reads P as
// A-frag, V^T as B-frag => oacc[dj][r] = O[q = qtile+4g+r][d = 16dj+c].
template<bool DIAG>
DEV void attn_qtile(const bf16x8 kf[4][2], const bf16x8 vf[4][2],
                    const bf16x8 qf[2], short (*ps)[72],
                    float& mrow, float& lsum, f32x4* oacc,
                    int g, int c, int qrow, int kv0) {
  f32x4 sacc[4] = {};
#pragma unroll
  for (int jt = 0; jt < 4; ++jt) {
    sacc[jt] = MFMA(kf[jt][0], qf[0], sacc[jt]);
    sacc[jt] = MFMA(kf[jt][1], qf[1], sacc[jt]);
  }
  float s2[4][4];
  float rmax = -1e30f;
#pragma unroll
  for (int jt = 0; jt < 4; ++jt) {
#pragma unroll
    for (int r = 0; r < 4; ++r) {
      float s = sacc[jt][r] * SCL2;
      if (DIAG) {
        const int kvi = kv0 + jt * 16 + 4 * g + r;
        s = (kvi <= qrow) ? s : -1e30f;
      }
      s2[jt][r] = s;
      rmax = fmaxf(rmax, s);
    }
  }
  rmax = fmaxf(rmax, __shfl_xor(rmax, 16, 64));
  rmax = fmaxf(rmax, __shfl_xor(rmax, 32, 64));
  const float mnew = fmaxf(mrow, rmax);
  const float scl = __builtin_amdgcn_exp2f(mrow - mnew);
  mrow = mnew;
  float rsum = 0.f;
#pragma unroll
  for (int jt = 0; jt < 4; ++jt) {
    const float p0 = __builtin_amdgcn_exp2f(s2[jt][0] - mnew);
    const float p1 = __builtin_amdgcn_exp2f(s2[jt][1] - mnew);
    const float p2 = __builtin_amdgcn_exp2f(s2[jt][2] - mnew);
    const float p3 = __builtin_amdgcn_exp2f(s2[jt][3] - mnew);
    rsum += (p0 + p1) + (p2 + p3);
    uint2 w;
    w.x = (unsigned)f2bf(p0) | ((unsigned)f2bf(p1) << 16);
    w.y = (unsigned)f2bf(p2) | ((unsigned)f2bf(p3) << 16);
    *(uint2*)&ps[c][jt * 16 + 4 * g] = w;
  }
  rsum += __shfl_xor(rsum, 16, 64);
  rsum += __shfl_xor(rsum, 32, 64);
  lsum = lsum * scl + rsum;

  float sclr[4];
#pragma unroll
  for (int r = 0; r < 4; ++r) sclr[r] = __shfl(scl, 4 * g + r, 64);
#pragma unroll
  for (int dj = 0; dj < 4; ++dj)
#pragma unroll
    for (int r = 0; r < 4; ++r) oacc[dj][r] *= sclr[r];

  const bf16x8 pf0 = *(const bf16x8*)&ps[c][g * 8];
  const bf16x8 pf1 = *(const bf16x8*)&ps[c][32 + g * 8];
#pragma unroll
  for (int dj = 0; dj < 4; ++dj) {
    oacc[dj] = MFMA(pf0, vf[dj][0], oacc[dj]);
    oacc[dj] = MFMA(pf1, vf[dj][1], oacc[dj]);
  }
}

__global__ __launch_bounds__(256, 2)
void attn2(const unsigned short* __restrict__ Qp,
           const unsigned short* __restrict__ Kp,
           const unsigned short* __restrict__ Vt,
           unsigned short* __restrict__ Ob) {
  __shared__ short Ks[2][64][72];
  __shared__ short Vs[2][64][72];
  __shared__ short Ps[64][72];
  const int tid = threadIdx.x;
  const int lane = tid & 63, wave = tid >> 6;
  const int g = lane >> 4, c = lane & 15;
  const int qbA = blockIdx.x;        // 0..15
  const int bh = blockIdx.y;         // 0..31
  const int b = bh >> 4, hd = bh & 15;
  const int jmax = 31 - qbA;         // q-tile B index (>=16)
  const int q0A = qbA * 64 + wave * 16;
  const int q0B = jmax * 64 + wave * 16;

  const unsigned short* Qbase = Qp + (long)b * LQ * DM + hd * DH;
  const unsigned short* Kbase = Kp + (long)b * LQ * DM + hd * DH;
  const unsigned short* Vbase = Vt + (long)bh * DH * LQ;

  bf16x8 qfA[2], qfB[2];
#pragma unroll
  for (int h = 0; h < 2; ++h) {
    qfA[h] = *(const bf16x8*)(Qbase + (long)(q0A + c) * DM + h * 32 + g * 8);
    qfB[h] = *(const bf16x8*)(Qbase + (long)(q0B + c) * DM + h * 32 + g * 8);
  }

  const int srow = tid >> 3;        // 0..31
  const int scol = (tid & 7) * 8;   // 0..56
  bf16x8 kr0, kr1, vr0, vr1;

#define LOAD_TILE(J)                                                         \
  {                                                                          \
    const unsigned short* kp_ = Kbase + (long)((J) * 64 + srow) * DM + scol; \
    kr0 = *(const bf16x8*)kp_;                                               \
    kr1 = *(const bf16x8*)(kp_ + 32 * DM);                                   \
    const unsigned short* vp_ = Vbase + (long)srow * LQ + (J) * 64 + scol;   \
    vr0 = *(const bf16x8*)vp_;                                               \
    vr1 = *(const bf16x8*)(vp_ + 32 * LQ);                                   \
  }
#define WRITE_TILE(BUF)                                                      \
  {                                                                          \
    *(bf16x8*)&Ks[BUF][srow][scol]      = kr0;                               \
    *(bf16x8*)&Ks[BUF][srow + 32][scol] = kr1;                               \
    *(bf16x8*)&Vs[BUF][srow][scol]      = vr0;                               \
    *(bf16x8*)&Vs[BUF][srow + 32][scol] = vr1;                               \
  }

  LOAD_TILE(0);
  WRITE_TILE(0);
  LOAD_TILE(1);   // jmax >= 16, always valid
  __syncthreads();

  float mA = -1e30f, lA = 0.f, mB = -1e30f, lB = 0.f;
  f32x4 oA[4] = {}, oB[4] = {};
  short (*ps)[72] = &Ps[wave * 16];

  for (int j = 0; j <= jmax; ++j) {
    const int cur = j & 1;
    if (j < jmax) WRITE_TILE(cur ^ 1);          // tile j+1 (regs) -> LDS
    if (j + 2 <= jmax) LOAD_TILE(j + 2);        // prefetch tile j+2 -> regs

    bf16x8 kf[4][2], vf[4][2];
#pragma unroll
    for (int jt = 0; jt < 4; ++jt) {
      kf[jt][0] = *(const bf16x8*)&Ks[cur][jt * 16 + c][g * 8];
      kf[jt][1] = *(const bf16x8*)&Ks[cur][jt * 16 + c][32 + g * 8];
      vf[jt][0] = *(const bf16x8*)&Vs[cur][jt * 16 + c][g * 8];
      vf[jt][1] = *(const bf16x8*)&Vs[cur][jt * 16 + c][32 + g * 8];
    }

    if (j < qbA)
      attn_qtile<false>(kf, vf, qfA, ps, mA, lA, oA, g, c, q0A + c, j * 64);
    else if (j == qbA)
      attn_qtile<true>(kf, vf, qfA, ps, mA, lA, oA, g, c, q0A + c, j * 64);

    if (j < jmax)
      attn_qtile<false>(kf, vf, qfB, ps, mB, lB, oB, g, c, q0B + c, j * 64);
    else
      attn_qtile<true>(kf, vf, qfB, ps, mB, lB, oB, g, c, q0B + c, j * 64);

    __syncthreads();
  }
#undef LOAD_TILE
#undef WRITE_TILE

  // epilogue: O /= lsum, store bf16 [b][l][DM]
#pragma unroll
  for (int it = 0; it < 2; ++it) {
    f32x4* oacc = it ? oB : oA;
    const float lsum = it ? lB : lA;
    const int q0 = it ? q0B : q0A;
#pragma unroll
    for (int r = 0; r < 4; ++r) {
      const float ls = __shfl(lsum, 4 * g + r, 64);
      const float inv = 1.0f / ls;
      const int q = q0 + 4 * g + r;
#pragma unroll
      for (int dj = 0; dj < 4; ++dj)
        Ob[((long)b * LQ + q) * DM + hd * DH + dj * 16 + c] =
            f2bf(oacc[dj][r] * inv);
    }
  }
}

// ---------------- launch --------------------------------------------------
extern "C" void kernel_launch(void* const* d_in, const int* in_sizes, int n_in,
                              void* d_out, int out_size, void* d_ws, size_t ws_size,
                              hipStream_t stream) {
  const float* q  = (const float*)d_in[0];
  const float* k  = (const float*)d_in[1];
  const float* v  = (const float*)d_in[2];
  const float* Wq = (const float*)d_in[3];
  const float* bq = (const float*)d_in[4];
  const float* Wk = (const float*)d_in[5];
  const float* bk = (const float*)d_in[6];
  const float* Wv = (const float*)d_in[7];
  const float* bv = (const float*)d_in[8];
  const float* Wo = (const float*)d_in[9];
  const float* bo = (const float*)d_in[10];

  unsigned short* ws = (unsigned short*)d_ws;
  const long NQKV = (long)MT * DM;   // 4,194,304 elems
  const long NW   = (long)DM * DM;   // 1,048,576 elems
  unsigned short* QB  = ws;          // q bf16 (reused as attn-out later)
  unsigned short* KB  = QB + NQKV;
  unsigned short* VB  = KB + NQKV;
  unsigned short* WQb = VB + NQKV;
  unsigned short* WKb = WQb + NW;
  unsigned short* WVb = WKb + NW;
  unsigned short* WOb = WVb + NW;
  unsigned short* QP  = WOb + NW;
  unsigned short* KP  = QP + NQKV;
  unsigned short* VT  = KP + NQKV;
  unsigned short* OB  = QB;          // alias: q bf16 dead after Q projection

  cvt3<<<dim3((int)(NQKV / 2048), 3), 256, 0, stream>>>(q, k, v, QB, KB, VB);
  cvt4<<<dim3((int)(NW / 2048), 4), 256, 0, stream>>>(Wq, Wk, Wv, Wo,
                                                      WQb, WKb, WVb, WOb);

  qkv_proj<<<dim3(8, 32, 3), 256, 0, stream>>>(QB, KB, VB, WQb, WKb, WVb,
                                               bq, bk, bv, QP, KP, VT);

  attn2<<<dim3(16, 32), 256, 0, stream>>>(QP, KP, VT, OB);

  oproj<<<dim3(8, 32), 256, 0, stream>>>(OB, WOb, bo, (float*)d_out);
}